// Round 4
// baseline (465.151 us; speedup 1.0000x reference)
//
#include <hip/hip_runtime.h>
#include <hip/hip_bf16.h>

typedef __attribute__((ext_vector_type(8))) short short8;
typedef __attribute__((ext_vector_type(4))) short short4v;
typedef __attribute__((ext_vector_type(4))) float floatx4;

#define S_LEN 4096
#define HIDDEN 2304
#define NHEADS 8
#define NKVH 4
#define HDIM 256
#define SWIN 2048

static __device__ __forceinline__ short bf16bits(float x) {
    __hip_bfloat16 h = __float2bfloat16(x);
    return __builtin_bit_cast(short, h);
}
static __device__ __forceinline__ float bits2f(short b) {
    return __bfloat162float(__builtin_bit_cast(__hip_bfloat16, b));
}

static __device__ __forceinline__ void gload_lds16(const short* g, short* l) {
    __builtin_amdgcn_global_load_lds((const __attribute__((address_space(1))) void*)g,
                                     (__attribute__((address_space(3))) void*)l,
                                     16, 0, 0);
}

// ---------------- one fused cast kernel: X, Wq, Wk, Wv, Wo -> bf16 regions ----------
// float4 counts: X 2359296 | Wq 1179648 | Wk 589824 | Wv 589824 | Wo 1179648  (total 5898240)
__global__ __launch_bounds__(256) void cast_all(const float* __restrict__ X,
                                                const float* __restrict__ Wq,
                                                const float* __restrict__ Wk,
                                                const float* __restrict__ Wv,
                                                const float* __restrict__ Wo,
                                                short* __restrict__ Xb,
                                                short* __restrict__ Wqkvb,
                                                short* __restrict__ Wob) {
    int i = blockIdx.x * 256 + threadIdx.x;
    const float4* src;
    short4v* dst;
    if (i < 2359296)      { src = (const float4*)X  + i;           dst = (short4v*)Xb    + i; }
    else if (i < 3538944) { src = (const float4*)Wq + (i-2359296); dst = (short4v*)Wqkvb + (i-2359296); }
    else if (i < 4128768) { src = (const float4*)Wk + (i-3538944); dst = (short4v*)Wqkvb + (i-2359296); }
    else if (i < 4718592) { src = (const float4*)Wv + (i-4128768); dst = (short4v*)Wqkvb + (i-2359296); }
    else                  { src = (const float4*)Wo + (i-4718592); dst = (short4v*)Wob   + (i-4718592); }
    float4 v = *src;
    short4v o;
    o.x = bf16bits(v.x); o.y = bf16bits(v.y); o.z = bf16bits(v.z); o.w = bf16bits(v.w);
    *dst = o;
}

// ---------------- generic GEMM (m97-style): C[M,N] = A[M,K]*B[N,K]^T ----------------
// MODE 0: bf16 row-major; MODE 2: fp32 row-major.
template<int MODE>
__global__ __launch_bounds__(256) void gemm_lds(const short* __restrict__ A,
                                                const short* __restrict__ B,
                                                void* __restrict__ Cp,
                                                int M, int N, int K, int ldc)
{
    __shared__ __align__(16) short lA[128 * 32];
    __shared__ __align__(16) short lB[128 * 32];
    int tid  = threadIdx.x;
    int lane = tid & 63;
    int wave = tid >> 6;
    int col  = lane & 15;
    int quad = lane >> 4;
    int m_base = blockIdx.y * 128;
    int n_base = blockIdx.x * 128;
    int wm = (wave >> 1) * 64;
    int wn = (wave & 1) * 64;

    int srow = wave * 32 + (lane >> 2);
    int scol = (lane & 3) * 8;
    const short* gA0 = A + (size_t)(m_base + srow) * K + scol;
    const short* gA1 = gA0 + (size_t)16 * K;
    const short* gB0 = B + (size_t)(n_base + srow) * K + scol;
    const short* gB1 = gB0 + (size_t)16 * K;
    short* lA0 = lA + wave * 1024;
    short* lB0 = lB + wave * 1024;

    floatx4 acc[4][4] = {};

    for (int k0 = 0; k0 < K; k0 += 32) {
        __syncthreads();
        gload_lds16(gA0 + k0, lA0);
        gload_lds16(gA1 + k0, lA0 + 512);
        gload_lds16(gB0 + k0, lB0);
        gload_lds16(gB1 + k0, lB0 + 512);
        __syncthreads();

        short8 af[4], bf[4];
        #pragma unroll
        for (int t = 0; t < 4; ++t) {
            af[t] = *(const short8*)(lA + (wm + t*16 + col) * 32 + quad * 8);
            bf[t] = *(const short8*)(lB + (wn + t*16 + col) * 32 + quad * 8);
        }
        #pragma unroll
        for (int mt = 0; mt < 4; ++mt)
            #pragma unroll
            for (int nt = 0; nt < 4; ++nt)
                acc[mt][nt] = __builtin_amdgcn_mfma_f32_16x16x32_bf16(af[mt], bf[nt], acc[mt][nt], 0, 0, 0);
    }

    #pragma unroll
    for (int mt = 0; mt < 4; ++mt) {
        #pragma unroll
        for (int nt = 0; nt < 4; ++nt) {
            int n  = n_base + wn + nt*16 + col;
            int m0 = m_base + wm + mt*16 + quad*4;
            if (MODE == 0) {
                short* C = (short*)Cp;
                #pragma unroll
                for (int r = 0; r < 4; ++r)
                    C[(size_t)(m0 + r) * ldc + n] = bf16bits(acc[mt][nt][r]);
            } else {
                float* C = (float*)Cp;
                #pragma unroll
                for (int r = 0; r < 4; ++r)
                    C[(size_t)(m0 + r) * ldc + n] = acc[mt][nt][r];
            }
        }
    }
}

// ---------------- fused QKV GEMM: A=Xb[4096][2304], B=Wqkvb[4096][2304] ----------------
// n in [0,3072): QKV[m][n] bf16 row-major (ld 4096).  Q cols 0..2047, K cols 2048..3071.
// n in [3072,4096): Vt[n-3072][m] transposed (ld 4096).
__global__ __launch_bounds__(256) void gemm_qkv(const short* __restrict__ A,
                                                const short* __restrict__ B,
                                                short* __restrict__ QKV,
                                                short* __restrict__ Vt)
{
    __shared__ __align__(16) short lA[128 * 32];
    __shared__ __align__(16) short lB[128 * 32];
    const int K = HIDDEN;
    int tid  = threadIdx.x;
    int lane = tid & 63;
    int wave = tid >> 6;
    int col  = lane & 15;
    int quad = lane >> 4;
    int m_base = blockIdx.y * 128;
    int n_base = blockIdx.x * 128;
    int wm = (wave >> 1) * 64;
    int wn = (wave & 1) * 64;

    int srow = wave * 32 + (lane >> 2);
    int scol = (lane & 3) * 8;
    const short* gA0 = A + (size_t)(m_base + srow) * K + scol;
    const short* gA1 = gA0 + (size_t)16 * K;
    const short* gB0 = B + (size_t)(n_base + srow) * K + scol;
    const short* gB1 = gB0 + (size_t)16 * K;
    short* lA0 = lA + wave * 1024;
    short* lB0 = lB + wave * 1024;

    floatx4 acc[4][4] = {};

    for (int k0 = 0; k0 < K; k0 += 32) {
        __syncthreads();
        gload_lds16(gA0 + k0, lA0);
        gload_lds16(gA1 + k0, lA0 + 512);
        gload_lds16(gB0 + k0, lB0);
        gload_lds16(gB1 + k0, lB0 + 512);
        __syncthreads();

        short8 af[4], bf[4];
        #pragma unroll
        for (int t = 0; t < 4; ++t) {
            af[t] = *(const short8*)(lA + (wm + t*16 + col) * 32 + quad * 8);
            bf[t] = *(const short8*)(lB + (wn + t*16 + col) * 32 + quad * 8);
        }
        #pragma unroll
        for (int mt = 0; mt < 4; ++mt)
            #pragma unroll
            for (int nt = 0; nt < 4; ++nt)
                acc[mt][nt] = __builtin_amdgcn_mfma_f32_16x16x32_bf16(af[mt], bf[nt], acc[mt][nt], 0, 0, 0);
    }

    #pragma unroll
    for (int mt = 0; mt < 4; ++mt) {
        #pragma unroll
        for (int nt = 0; nt < 4; ++nt) {
            int n  = n_base + wn + nt*16 + col;
            int m0 = m_base + wm + mt*16 + quad*4;
            if (n_base + wn + nt*16 < 3072) {
                #pragma unroll
                for (int r = 0; r < 4; ++r)
                    QKV[(size_t)(m0 + r) * 4096 + n] = bf16bits(acc[mt][nt][r]);
            } else {
                short4v v;
                v.x = bf16bits(acc[mt][nt][0]);
                v.y = bf16bits(acc[mt][nt][1]);
                v.z = bf16bits(acc[mt][nt][2]);
                v.w = bf16bits(acc[mt][nt][3]);
                *(short4v*)(Vt + (size_t)(n - 3072) * 4096 + m0) = v;
            }
        }
    }
}

// ---------------- RoPE, in-place on QKV [S][4096] (q cols 0..2047, k cols 2048..3071) --
__global__ __launch_bounds__(256) void rope_kernel(short* __restrict__ QKV,
                                                   const int* __restrict__ pos)
{
    int t = blockIdx.x * 256 + threadIdx.x;   // S * 12 * 128 threads
    int d   = t & 127;
    int rem = t >> 7;
    int hh  = rem % 12;                        // 0..7 q-heads, 8..11 k-heads
    int s   = rem / 12;
    float p   = (float)pos[s];
    float inv = __expf(-9.210340371976184f * ((float)d * (1.0f/128.0f)));  // 10000^(-d/128)
    float ang = p * inv;
    float sn, cs;
    sincosf(ang, &sn, &cs);
    short* row = QKV + (size_t)s * 4096 + hh * 256;
    float x1 = bits2f(row[d]);
    float x2 = bits2f(row[d + 128]);
    row[d]       = bf16bits(x1 * cs - x2 * sn);
    row[d + 128] = bf16bits(x2 * cs + x1 * sn);
}

// ---------------- flash attention: block = 4 waves = 64 queries, one head ------------
// Double-buffered K/V staging (global_load_lds), ONE barrier per 32-key tile:
//   barrier at loop top drains the stage issued last iter; then issue next stage;
//   then compute current tile (drain latency hidden behind compute).
// lK layout [c][key][sub]: c*1024 + key*32 + sub*8; lV layout [d][ks]: d*32 + ks*8.
// lP is wave-private (no barrier needed). Fixed-max softmax p = exp(sv-12).
__global__ __launch_bounds__(256) void attn_kernel(const short* __restrict__ QKV,
                                                   const short* __restrict__ Vt,
                                                   short* __restrict__ Ob)
{
    __shared__ __align__(16) short lK[2][32 * 256];   // 2 x 16 KB
    __shared__ __align__(16) short lV[2][256 * 32];   // 2 x 16 KB
    __shared__ __align__(16) short lP[4][16 * 40];    // 5 KB (stride 40 pads banks)
    int tid  = threadIdx.x;
    int lane = tid & 63;
    int wave = tid >> 6;
    int col  = lane & 15;
    int quad = lane >> 4;
    int bid  = blockIdx.x;             // g*128 + pair*2 + hsub; heavy (large-window) first
    int g     = bid >> 7;
    int chunk = 63 - ((bid >> 1) & 63);
    int h     = g * 2 + (bid & 1);
    int qb = chunk * 64;
    int q0 = qb + wave * 16;

    // preload Q fragments (A-operand: m=col, k=quad*8+j), HD=256 in 8 chunks
    const short* Qrow = QKV + (size_t)(q0 + col) * 4096 + h * 256;
    short8 qf[8];
    #pragma unroll
    for (int c = 0; c < 8; ++c)
        qf[c] = *(const short8*)(Qrow + c*32 + quad*8);

    // staging source/dest descriptors (per-lane; LDS base wave-uniform)
    int k_key = (lane >> 2);
    int k_sub = (lane & 3) * 8;
    const short* gK[2][2];
    int dKo[2][2];
    #pragma unroll
    for (int cc = 0; cc < 2; ++cc)
        #pragma unroll
        for (int hh = 0; hh < 2; ++hh) {
            int c = 2*wave + cc;
            gK[cc][hh] = QKV + (size_t)(hh*16 + k_key) * 4096 + 2048 + g*256 + c*32 + k_sub;
            dKo[cc][hh] = c*1024 + hh*512;
        }
    const short* gV[4];
    int dVo[4];
    #pragma unroll
    for (int jj = 0; jj < 4; ++jj) {
        int j = 4*wave + jj;
        gV[jj] = Vt + (size_t)(g*256 + j*16 + k_key) * 4096 + (lane & 3) * 8;
        dVo[jj] = j*512;
    }

    floatx4 o[16] = {};
    float psum[4] = {0.f, 0.f, 0.f, 0.f};

    int kb_start = qb - (SWIN - 1);
    if (kb_start < 0) kb_start = 0;
    kb_start &= ~31;
    int kb_end = qb + 64;

    // prologue: stage first tile into buffer 0
    #pragma unroll
    for (int cc = 0; cc < 2; ++cc)
        #pragma unroll
        for (int hh = 0; hh < 2; ++hh)
            gload_lds16(gK[cc][hh] + (size_t)kb_start * 4096, &lK[0][0] + dKo[cc][hh]);
    #pragma unroll
    for (int jj = 0; jj < 4; ++jj)
        gload_lds16(gV[jj] + kb_start, &lV[0][0] + dVo[jj]);

    int ib = 0;
    for (int kb = kb_start; kb < kb_end; kb += 32, ib ^= 1) {
        __syncthreads();   // drains last iter's staging (vmcnt0) + syncs readers of other buf

        int kn = kb + 32;
        if (kn < kb_end) {
            #pragma unroll
            for (int cc = 0; cc < 2; ++cc)
                #pragma unroll
                for (int hh = 0; hh < 2; ++hh)
                    gload_lds16(gK[cc][hh] + (size_t)kn * 4096, &lK[ib^1][0] + dKo[cc][hh]);
            #pragma unroll
            for (int jj = 0; jj < 4; ++jj)
                gload_lds16(gV[jj] + kn, &lV[ib^1][0] + dVo[jj]);
        }

        const short* Kc = &lK[ib][0];
        const short* Vc = &lV[ib][0];

        // ---- QK^T from LDS ----
        floatx4 sc[2] = {};
        #pragma unroll
        for (int t = 0; t < 2; ++t)
            #pragma unroll
            for (int c = 0; c < 8; ++c) {
                short8 kf = *(const short8*)(Kc + c*1024 + (t*16 + col)*32 + quad*8);
                sc[t] = __builtin_amdgcn_mfma_f32_16x16x32_bf16(qf[c], kf, sc[t], 0, 0, 0);
            }

        // ---- scale, softcap (poly tanh), mask, exp(sv-12) ----
        int j0 = kb + col;
        int j1 = kb + 16 + col;
        #pragma unroll
        for (int r = 0; r < 4; ++r) {
            int i = q0 + quad*4 + r;
            float y0 = sc[0][r] * 0.0625f;
            float y1 = sc[1][r] * 0.0625f;
            float x20 = y0 * y0 * 4.0e-4f;
            float x21 = y1 * y1 * 4.0e-4f;
            float sv0 = y0 * (1.0f + x20 * (-0.33333333f + x20 * 0.13333333f));
            float sv1 = y1 * (1.0f + x21 * (-0.33333333f + x21 * 0.13333333f));
            bool v0 = (j0 <= i) && ((i - j0) < SWIN);
            bool v1 = (j1 <= i) && ((i - j1) < SWIN);
            float p0 = v0 ? __expf(sv0 - 12.0f) : 0.0f;
            float p1 = v1 ? __expf(sv1 - 12.0f) : 0.0f;
            lP[wave][(quad*4 + r)*40 + col]      = bf16bits(p0);
            lP[wave][(quad*4 + r)*40 + 16 + col] = bf16bits(p1);
            psum[r] += p0 + p1;
        }
        __threadfence_block();   // order P write -> read (wave-private transpose)
        short8 pa = *(const short8*)(&lP[wave][col*40 + quad*8]);

        // ---- PV from LDS ----
        #pragma unroll
        for (int nt = 0; nt < 16; ++nt) {
            short8 vf = *(const short8*)(Vc + (nt*16 + col)*32 + quad*8);
            o[nt] = __builtin_amdgcn_mfma_f32_16x16x32_bf16(pa, vf, o[nt], 0, 0, 0);
        }
    }

    // ---- epilogue: reduce l over 16 col-lanes, store Ob = o/l ----
    #pragma unroll
    for (int off = 1; off < 16; off <<= 1)
        #pragma unroll
        for (int r = 0; r < 4; ++r)
            psum[r] += __shfl_xor(psum[r], off, 64);

    #pragma unroll
    for (int nt = 0; nt < 16; ++nt)
        #pragma unroll
        for (int r = 0; r < 4; ++r) {
            int i = q0 + quad*4 + r;
            Ob[(size_t)i * 2048 + h*256 + nt*16 + col] = bf16bits(o[nt][r] / psum[r]);
        }
}

// ---------------- launcher ----------------
extern "C" void kernel_launch(void* const* d_in, const int* in_sizes, int n_in,
                              void* d_out, int out_size, void* d_ws, size_t ws_size,
                              hipStream_t stream)
{
    const float* X  = (const float*)d_in[0];
    const int*  pos = (const int*)d_in[1];
    const float* Wq = (const float*)d_in[2];
    const float* Wk = (const float*)d_in[3];
    const float* Wv = (const float*)d_in[4];
    const float* Wo = (const float*)d_in[5];
    float* out = (float*)d_out;
    char* ws = (char*)d_ws;

    // workspace layout (bytes); Ob overlaps Xb (dead after gemm_qkv)
    short* Xb    = (short*)(ws + 0);          // 4096x2304 bf16 = 18,874,368
    short* Wqkvb = (short*)(ws + 18874368);   // 4096x2304 bf16 = 18,874,368
    short* Wob   = (short*)(ws + 37748736);   // 2304x2048 bf16 =  9,437,184
    short* QKVb  = (short*)(ws + 47185920);   // 4096x4096 bf16 = 33,554,432
    short* Vt    = (short*)(ws + 80740352);   // 1024x4096 bf16 =  8,388,608  (end 89,128,960)
    short* Ob    = (short*)(ws + 0);          // 4096x2048 bf16 = 16,777,216  (reuses Xb)

    cast_all<<<23040, 256, 0, stream>>>(X, Wq, Wk, Wv, Wo, Xb, Wqkvb, Wob);

    gemm_qkv<<<dim3(32,32), 256, 0, stream>>>(Xb, Wqkvb, QKVb, Vt);

    rope_kernel<<<24576, 256, 0, stream>>>(QKVb, pos);

    attn_kernel<<<512, 256, 0, stream>>>(QKVb, Vt, Ob);

    gemm_lds<2><<<dim3(18,32), 256, 0, stream>>>(Ob, Wob, out, 4096, 2304, 2048, 2304);
}